// Round 8
// baseline (29698.233 us; speedup 1.0000x reference)
//
#include <hip/hip_runtime.h>
#include <math.h>

#define NSTATES 1024
#define TT      4096
#define DD      20

#define FW_BLOCKS  64      // worker blocks (virtual), all on ONE XCD
#define FW_GRID    512     // launched blocks; 448 exit after election
#define FW_THREADS 256
#define JPB  16      // j per block   (FW_BLOCKS * JPB = NSTATES)
#define NSEG 16      // k segments    (JPB * NSEG = FW_THREADS)
#define KSEG 64      // k per segment (NSEG * KSEG = NSTATES)

#define SENT 0x7FC00000u   // canonical NaN: computed column values are never NaN

// workspace layout (bytes)
#define OFF_LAT   ((size_t)0)               // 4 MB  logA transposed: lat[j*N+k] = log(trans[k][j])
#define OFF_E     ((size_t)4 << 20)         // 16 MB emissions E[t*N+n]
#define OFF_COLS  ((size_t)20 << 20)        // 16 MB per-step columns cols[t*N+j]
#define OFF_PTR   ((size_t)36 << 20)        // 8 MB  u16 backpointers, rows 1..T-1
// election state lives in bptr row 0 (2 KB, otherwise dead):
//   u32[0] = winner xcd (init ~0), u32[16 + x*16] = ticket counter for xcd x.

typedef unsigned int u32;
typedef u32 u32x4 __attribute__((ext_vector_type(4)));

#define ALD(p) __hip_atomic_load((p), __ATOMIC_RELAXED, __HIP_MEMORY_SCOPE_AGENT)

__global__ void k_init(uint4* __restrict__ cols4) {
    // fill 16 MB of cols with the sentinel (4M words = 1M uint4)
    int id = blockIdx.x * 256 + threadIdx.x;
    cols4[id] = make_uint4(SENT, SENT, SENT, SENT);
}

__global__ void k_elect_init(u32* __restrict__ el) {
    int id = threadIdx.x;                   // 1 block x 64
    if (id == 0) el[0] = 0xFFFFFFFFu;       // winner = none
    if (id < 8)  el[16 + id * 16] = 0u;     // per-xcd ticket counters
}

__global__ void k_logtrans(const float* __restrict__ tr, float* __restrict__ lat) {
    int id = blockIdx.x * 256 + threadIdx.x;        // 1M threads
    int k = id >> 10, j = id & 1023;
    lat[(size_t)j * NSTATES + k] = logf(tr[id]);    // coalesced read, strided write (one-time)
}

__global__ void k_emis(const float* __restrict__ ev, const float* __restrict__ epar,
                       const float* __restrict__ prior, float* __restrict__ E,
                       float* __restrict__ cols) {
    int n = blockIdx.x * 256 + threadIdx.x;         // 4 x 256 = 1024
    int t = blockIdx.y;                             // 0..4095
    const float* ep = epar + (size_t)n * (2 * DD);
    const float* x  = ev + (size_t)t * DD;
    float acc = 0.0f;
    #pragma unroll
    for (int d = 0; d < DD; ++d) {
        float m = ep[2 * d];
        float s = ep[2 * d + 1];
        // faithful to reference: p = (2*pi*s)^(-0.5) * exp(-(x-m)^2/(2*s^2)); logp = log(p)
        float tp   = 6.2831853071795864769f * s;
        float coef = 1.0f / sqrtf(tp);
        float df   = x[d] - m;
        float num  = df * df;
        float den  = 2.0f * (s * s);
        float p    = coef * expf(-num / den);
        acc += logf(p);                             // -inf propagates; values are never NaN
    }
    E[(size_t)t * NSTATES + n] = acc;
    if (t == 0) cols[n] = logf(prior[n]) + acc;     // col0 = log(prior) + logp0 (overwrites sentinel)
}

// Forward pass: R3 protocol shape byte-for-byte, with the rendezvous moved
// from the LLC into ONE XCD's L2.
//   election: 512 blocks ticket on per-xcd counters keyed by HW_REG_XCC_ID;
//             pigeonhole guarantees an xcd reaches 64 tickets; its 64th block
//             CASes winner. 64 winning blocks (tickets 0..63) work; rest exit.
//   poll:     global_load_dwordx4 sc0 (SE scope: bypass per-CU L1, served by
//             the XCD-shared L2 = the coherence point for all worker CUs).
//   publish:  global_store_dword sc0 (write-through to the same L2).
//   safety:   every 32 failed sc0 sweeps, one agent-scope ALD sweep (L2 must
//             serve its own dirty lines to device-scope reads) may satisfy
//             the exit; a persistent guard force-fails (NaN propagates ->
//             clean absmax failure) rather than hanging.
__global__ __launch_bounds__(FW_THREADS, 1) void k_forward(
    const float* __restrict__ lat, const float* __restrict__ E,
    float* __restrict__ cols, unsigned short* __restrict__ bptr,
    u32* __restrict__ elect)
{
    __shared__ int s_vb;
    // padded [16][68]: row r holds words [r*64, r*64+64) of the prev column.
    __shared__ __align__(16) float prevs[NSEG * 68];
    __shared__ float          smaxw[4][JPB];   // per-wave partials (segs 4w..4w+3)
    __shared__ unsigned short sidxw[4][JPB];
    const int tid  = threadIdx.x;

    // ---- XCD election (one thread per block) ----
    if (tid == 0) {
        u32 xcc;
        asm volatile("s_getreg_b32 %0, hwreg(HW_REG_XCC_ID)" : "=s"(xcc));
        xcc &= 7u;
        u32 tk = __hip_atomic_fetch_add(elect + 16 + xcc * 16, 1u,
                                        __ATOMIC_RELAXED, __HIP_MEMORY_SCOPE_AGENT);
        int vb = -1;
        if (tk < (u32)FW_BLOCKS) {
            if (tk == (u32)(FW_BLOCKS - 1)) {   // 64th block on this xcd: claim
                u32 exp = 0xFFFFFFFFu;
                __hip_atomic_compare_exchange_strong(elect, &exp, xcc,
                    __ATOMIC_RELAXED, __ATOMIC_RELAXED, __HIP_MEMORY_SCOPE_AGENT);
            }
            u32 w;
            for (;;) {                           // winner is guaranteed to be set
                w = ALD(elect);
                if (w != 0xFFFFFFFFu) break;
                __builtin_amdgcn_s_sleep(8);
            }
            if (w == xcc) vb = (int)tk;
        }
        s_vb = vb;
    }
    __syncthreads();
    const int vb = s_vb;
    if (vb < 0) return;                          // non-worker: free the CU

    const int seg  = tid >> 4;                  // 0..15: k in [seg*64, seg*64+64)
    const int jj   = tid & (JPB - 1);
    const int wav  = tid >> 6;                  // wave id 0..3 (holds segs 4w..4w+3)
    const int j0   = vb * JPB;
    const int j    = j0 + jj;
    const float lat00 = lat[0];                 // log trans[0][0], for the j==0 quirk

    // preload this thread's lat slice into registers (loop-invariant, 64 VGPRs)
    float4 latr[16];
    {
        const float* lrow = lat + (size_t)j * NSTATES + seg * KSEG;
        #pragma unroll
        for (int u = 0; u < 16; ++u) latr[u] = *(const float4*)(lrow + u * 4);
    }

    // thread stages its 4 polled words at padded (row tid>>4, col (tid&15)*4)
    float* dstp = &prevs[(tid >> 4) * 68 + (tid & 15) * 4];
    const float* rowp = &prevs[seg * 68];

    unsigned long long guard = 0;               // anti-hang failsafe

    for (int t = 1; t < TT; ++t) {
        // E prefetch: issued before the poll; drains under the poll's wait.
        float e = E[(size_t)t * NSTATES + j];

        // ---- poll previous column: one dwordx4 sc0 sweep (L2-served),
        // per-thread exit; R3's s_sleep backoff; ALD fallback + guard.
        const u32* p = (const u32*)(cols + (size_t)(t - 1) * NSTATES) + tid * 4;
        u32x4 A;
        int tries = 0;
        for (;;) {
            asm volatile(
                "global_load_dwordx4 %0, %1, off sc0\n\t"
                "s_waitcnt vmcnt(0)"
                : "=&v"(A) : "v"(p) : "memory");
            if (A.x != SENT && A.y != SENT && A.z != SENT && A.w != SENT) break;
            if (++tries >= 32) {
                u32 a0 = ALD(p + 0), a1 = ALD(p + 1), a2 = ALD(p + 2), a3 = ALD(p + 3);
                if (a0 != SENT && a1 != SENT && a2 != SENT && a3 != SENT) {
                    A = (u32x4){a0, a1, a2, a3};
                    break;
                }
                tries = 0;
                guard += 32;
                if (guard > (1ull << 23)) break;   // fail clean (NaN), never hang
            }
            __builtin_amdgcn_s_sleep(1);
        }
        {
            float4 v;
            v.x = __uint_as_float(A.x);
            v.y = __uint_as_float(A.y);
            v.z = __uint_as_float(A.z);
            v.w = __uint_as_float(A.w);
            *(float4*)dstp = v;                 // padded b128 store, conflict-free
        }
        __syncthreads();                        // barrier 1: staging visible to all

        // ---- scan this thread's 64 k's for its j: first-max (strict >, asc k)
        float best = -__builtin_inff();
        int bidx = seg * KSEG;
        #pragma unroll
        for (int u = 0; u < 16; ++u) {
            float4 q  = *(const float4*)(rowp + u * 4);   // 16-lane broadcast
            float4 wv = latr[u];
            int k0 = seg * KSEG + u * 4;
            float v0 = q.x + wv.x;
            float v1 = q.y + wv.y;
            float v2 = q.z + wv.z;
            float v3 = q.w + wv.w;
            if (v0 > best) { best = v0; bidx = k0;     }
            if (v1 > best) { best = v1; bidx = k0 + 1; }
            if (v2 > best) { best = v2; bidx = k0 + 2; }
            if (v3 > best) { best = v3; bidx = k0 + 3; }
        }

        // ---- combine the wave's 4 segs per j via shfl (disjoint ascending k
        // ranges: tie -> smaller bidx == sequential first-max). No sync.
        {
            float ov = __shfl_xor(best, 16);
            int   oi = __shfl_xor(bidx, 16);
            if (ov > best || (ov == best && oi < bidx)) { best = ov; bidx = oi; }
            ov = __shfl_xor(best, 32);
            oi = __shfl_xor(bidx, 32);
            if (ov > best || (ov == best && oi < bidx)) { best = ov; bidx = oi; }
        }
        if ((tid & 63) < JPB) {                 // one lane per (wave, jj)
            smaxw[wav][jj] = best;
            sidxw[wav][jj] = (unsigned short)bidx;
        }
        __syncthreads();                        // barrier 2: partials visible

        // ---- final 4-deep combine (ascending wave == ascending seg) + publish
        if (tid < JPB) {
            float m = smaxw[0][tid];
            int  mi = sidxw[0][tid];
            #pragma unroll
            for (int ww = 1; ww < 4; ++ww) {
                float v = smaxw[ww][tid];
                if (v > m) { m = v; mi = sidxw[ww][tid]; }
            }
            int jw = j0 + tid;
            // reference quirk: j==0 forced from state 0; prevs[0] (staged by
            // tid 0, wave 0 -- not yet overwritten) is cols[t-1][0].
            float val = (jw == 0) ? (prevs[0] + lat00) : m;
            float out = val + e;                // e: jj == tid for tid < 16
            u32* op = (u32*)(cols + (size_t)t * NSTATES) + jw;
            u32  ov = __float_as_uint(out);
            // SE-scope publish: write-through to the worker XCD's shared L2
            asm volatile("global_store_dword %0, %1, off sc0"
                         :: "v"(op), "v"(ov) : "memory");
            bptr[(size_t)t * NSTATES + jw] = (unsigned short)mi;
        }
        // no third barrier: next iteration's staging only overwrites prevs rows
        // whose readers (scans) completed before barrier 2; smaxw reuse is
        // ordered by the next iteration's barrier 1.
    }
}

// Double-buffered backtrace (verified in rounds 6-7): 255 threads stage
// chunk c+1 from HBM while lane 0 chases chunk c through LDS.
#define BTC 16  // ptr rows per LDS chunk; 2 buffers x 16 rows x 2KB = 64 KB
__global__ void k_backtrace(const float* __restrict__ lastcol,
                            const unsigned short* __restrict__ bptr,
                            int* __restrict__ seq)
{
    __shared__ unsigned short ring[2][BTC][NSTATES];
    __shared__ int s_front;
    const int tid = threadIdx.x;    // 256 threads

    // last = first-max argmax over final column (wave 0)
    if (tid < 64) {
        float best = -__builtin_inff();
        int bi = 0;
        for (int n2 = tid; n2 < NSTATES; n2 += 64) {
            float v = lastcol[n2];
            if (v > best) { best = v; bi = n2; }
        }
        #pragma unroll
        for (int off = 32; off > 0; off >>= 1) {
            float ov = __shfl_xor(best, off);
            int   oi = __shfl_xor(bi, off);
            if (ov > best || (ov == best && oi < bi)) { best = ov; bi = oi; }
        }
        if (tid == 0) { seq[TT] = bi; seq[TT - 1] = bi; s_front = bi; }
    }
    __syncthreads();

    // chunks descend: chunk c covers rows rhi=TT-1-c*BTC .. max(rhi-BTC+1, 1).
    auto stage = [&](int c, int buf, int t0, int stride) {
        int rhi = TT - 1 - c * BTC;
        int rlo = rhi - (BTC - 1); if (rlo < 1) rlo = 1;
        int n4 = (rhi - rlo + 1) * 128;                 // uint4 per chunk
        uint4* dst = (uint4*)&ring[buf][0][0];
        for (int idx = t0; idx < n4; idx += stride) {
            int ro = idx >> 7, wo = idx & 127;
            dst[idx] = ((const uint4*)(bptr + (size_t)(rhi - ro) * NSTATES))[wo];
        }
    };
    const int nc = (TT - 1 + BTC - 1) / BTC;            // 256
    stage(0, 0, tid, 256);
    __syncthreads();
    for (int c = 0; c < nc; ++c) {
        int buf = c & 1;
        if (tid != 0) {
            if (c + 1 < nc) stage(c + 1, buf ^ 1, tid - 1, 255);
        } else {
            int rhi = TT - 1 - c * BTC;
            int rlo = rhi - (BTC - 1); if (rlo < 1) rlo = 1;
            int front = s_front;
            for (int r = rhi; r >= rlo; --r) {
                front = (int)ring[buf][rhi - r][front];
                seq[r - 1] = front;
            }
            s_front = front;
        }
        __syncthreads();
    }
}

extern "C" void kernel_launch(void* const* d_in, const int* in_sizes, int n_in,
                              void* d_out, int out_size, void* d_ws, size_t ws_size,
                              hipStream_t stream) {
    const float* ev    = (const float*)d_in[0];   // [T, D]
    const float* prior = (const float*)d_in[1];   // [N]
    const float* tr    = (const float*)d_in[2];   // [N, N]
    const float* epar  = (const float*)d_in[3];   // [N, D, 2]
    int* seq = (int*)d_out;                       // [T+1]
    char* ws = (char*)d_ws;
    float* lat  = (float*)(ws + OFF_LAT);
    float* E    = (float*)(ws + OFF_E);
    float* cols = (float*)(ws + OFF_COLS);
    unsigned short* bptr = (unsigned short*)(ws + OFF_PTR);
    u32* elect = (u32*)(ws + OFF_PTR);            // bptr row 0 (dead) = election

    k_init<<<4096, 256, 0, stream>>>((uint4*)cols);              // sentinel-fill 16 MB
    k_elect_init<<<1, 64, 0, stream>>>(elect);
    k_logtrans<<<4096, 256, 0, stream>>>(tr, lat);
    k_emis<<<dim3(4, TT), 256, 0, stream>>>(ev, epar, prior, E, cols);
    k_forward<<<FW_GRID, FW_THREADS, 0, stream>>>(lat, E, cols, bptr, elect);
    k_backtrace<<<1, 256, 0, stream>>>(cols + (size_t)(TT - 1) * NSTATES, bptr, seq);
}

// Round 9
// 10512.460 us; speedup vs baseline: 2.8251x; 2.8251x over previous
//
#include <hip/hip_runtime.h>
#include <math.h>

#define NSTATES 1024
#define TT      4096
#define DD      20

#define FW_BLOCKS  64
#define FW_THREADS 256
#define JPB  16      // j per block   (FW_BLOCKS * JPB = NSTATES)
#define NSEG 16      // k segments    (JPB * NSEG = FW_THREADS)
#define KSEG 64      // k per segment (NSEG * KSEG = NSTATES)

#define SENT 0x7FC00000u   // canonical NaN: computed column values are never NaN

// workspace layout (bytes)
#define OFF_LAT   ((size_t)0)               // 4 MB  logA transposed: lat[j*N+k] = log(trans[k][j])
#define OFF_COLS  ((size_t)20 << 20)        // 16 MB per-step columns cols[t*N+j]
#define OFF_PTR   ((size_t)36 << 20)        // 8 MB  u16 backpointers, rows 1..T-1

typedef unsigned int u32;

__global__ void k_init(uint4* __restrict__ cols4) {
    // fill 16 MB of cols with the sentinel (4M words = 1M uint4)
    int id = blockIdx.x * 256 + threadIdx.x;
    cols4[id] = make_uint4(SENT, SENT, SENT, SENT);
}

__global__ void k_logtrans(const float* __restrict__ tr, float* __restrict__ lat) {
    int id = blockIdx.x * 256 + threadIdx.x;        // 1M threads
    int k = id >> 10, j = id & 1023;
    lat[(size_t)j * NSTATES + k] = logf(tr[id]);    // coalesced read, strided write (one-time)
}

// Forward pass: R3/R7 handoff protocol byte-for-byte (verified local optimum
// across 4 failed protocol attacks: R4 cadence, R5 traffic, R6 flag-split,
// R8 L1-stale sc0). NEW: emission computation FUSED into the step loop.
//   - k_emis (~850us of serial dispatch: 84M transcendentals for 16 MB of E,
//     of which each block ever uses 320 values/step) is deleted.
//   - each block computes its own 16j x 20d log-p slice at loop top (~300cy,
//     hidden in the ~2us poll dead time; R3 ablation: +/-600cy intra-block is
//     invisible under poll-period quantization).
//   - per-(j,d) values staged in double-buffered LDS; publisher lane sums d
//     ascending (same serial order as reference => bit-identical), adds
//     logf(prior) at t=0, publishes col0 through the standard protocol.
__global__ __launch_bounds__(FW_THREADS, 1) void k_forward(
    const float* __restrict__ lat, const float* __restrict__ ev,
    const float* __restrict__ epar, const float* __restrict__ prior,
    float* __restrict__ cols, unsigned short* __restrict__ bptr)
{
    // padded [16][68]: row r holds words [r*64, r*64+64) of the prev column.
    __shared__ __align__(16) float prevs[NSEG * 68];
    __shared__ float          smaxw[4][JPB];   // per-wave partials (segs 4w..4w+3)
    __shared__ unsigned short sidxw[4][JPB];
    __shared__ float          elp[2][JPB][DD]; // double-buffered emission log-p
    const int tid  = threadIdx.x;
    const int seg  = tid >> 4;                  // 0..15: k in [seg*64, seg*64+64)
    const int jj   = tid & (JPB - 1);
    const int wav  = tid >> 6;                  // wave id 0..3 (holds segs 4w..4w+3)
    const int j0   = blockIdx.x * JPB;
    const int j    = j0 + jj;
    const float lat00 = lat[0];                 // log trans[0][0], for the j==0 quirk

    // ---- fused-emission per-thread constants (items: it0 = tid, it1 = tid+256)
    // item -> (jj_e = item/20, d_e = item%20); 320 items cover 16j x 20d.
    const int jj0e = tid / DD, d0e = tid % DD;
    const float m0 = epar[((size_t)(j0 + jj0e) * DD + d0e) * 2 + 0];
    const float s0 = epar[((size_t)(j0 + jj0e) * DD + d0e) * 2 + 1];
    const float coef0 = 1.0f / sqrtf(6.2831853071795864769f * s0);
    const float den0  = 2.0f * (s0 * s0);
    const bool  has1  = (tid + 256) < JPB * DD;     // tid < 64
    const int   it1   = tid + 256;
    const int jj1e = has1 ? it1 / DD : 0, d1e = has1 ? it1 % DD : 0;
    const float m1 = has1 ? epar[((size_t)(j0 + jj1e) * DD + d1e) * 2 + 0] : 0.0f;
    const float s1 = has1 ? epar[((size_t)(j0 + jj1e) * DD + d1e) * 2 + 1] : 1.0f;
    const float coef1 = 1.0f / sqrtf(6.2831853071795864769f * s1);
    const float den1  = 2.0f * (s1 * s1);

    // faithful to reference: p = (2*pi*s)^(-0.5) * exp(-(x-m)^2/(2*s^2));
    // logp = log(p). -inf (p underflow) propagates; never NaN. Expression
    // sequence copied verbatim from the verified k_emis.
    auto emis = [&](int t, int buf) {
        float x0  = ev[(size_t)t * DD + d0e];
        float df0 = x0 - m0;
        float num0 = df0 * df0;
        float p0  = coef0 * expf(-num0 / den0);
        elp[buf][jj0e][d0e] = logf(p0);
        if (has1) {
            float x1  = ev[(size_t)t * DD + d1e];
            float df1 = x1 - m1;
            float num1 = df1 * df1;
            float p1  = coef1 * expf(-num1 / den1);
            elp[buf][jj1e][d1e] = logf(p1);
        }
    };

    // preload this thread's lat slice into registers (loop-invariant)
    float4 latr[16];
    {
        const float* lrow = lat + (size_t)j * NSTATES + seg * KSEG;
        #pragma unroll
        for (int u = 0; u < 16; ++u) latr[u] = *(const float4*)(lrow + u * 4);
    }

    // thread stages its 4 polled words at padded (row tid>>4, col (tid&15)*4)
    float* dstp = &prevs[(tid >> 4) * 68 + (tid & 15) * 4];
    const float* rowp = &prevs[seg * 68];

    // ---- t = 0: compute + publish col0 through the standard protocol ----
    emis(0, 0);
    __syncthreads();
    if (tid < JPB) {
        float acc = 0.0f;
        #pragma unroll
        for (int d = 0; d < DD; ++d) acc += elp[0][tid][d];   // ascending d
        float c0 = logf(prior[j0 + tid]) + acc;
        __hip_atomic_store((u32*)cols + (j0 + tid), __float_as_uint(c0),
                           __ATOMIC_RELAXED, __HIP_MEMORY_SCOPE_AGENT);
    }

    for (int t = 1; t < TT; ++t) {
        // emission slice for this step: computed in poll dead time; elp
        // buffer t&1 (col0 used buf 0; reuse at t+2 is gated by barrier2(t+1))
        emis(t, t & 1);

        // ---- poll previous column: 4 relaxed agent-scope word loads/thread,
        // per-thread exit (the proven protocol).
        const u32* p = (const u32*)(cols + (size_t)(t - 1) * NSTATES) + tid * 4;
        u32 w0, w1, w2, w3;
        for (;;) {
            w0 = __hip_atomic_load(p + 0, __ATOMIC_RELAXED, __HIP_MEMORY_SCOPE_AGENT);
            w1 = __hip_atomic_load(p + 1, __ATOMIC_RELAXED, __HIP_MEMORY_SCOPE_AGENT);
            w2 = __hip_atomic_load(p + 2, __ATOMIC_RELAXED, __HIP_MEMORY_SCOPE_AGENT);
            w3 = __hip_atomic_load(p + 3, __ATOMIC_RELAXED, __HIP_MEMORY_SCOPE_AGENT);
            if (w0 != SENT && w1 != SENT && w2 != SENT && w3 != SENT) break;
            __builtin_amdgcn_s_sleep(1);
        }
        {
            float4 v;
            v.x = __uint_as_float(w0);
            v.y = __uint_as_float(w1);
            v.z = __uint_as_float(w2);
            v.w = __uint_as_float(w3);
            *(float4*)dstp = v;                 // padded b128 store, conflict-free
        }
        __syncthreads();                        // barrier 1: staging + elp visible

        // ---- scan this thread's 64 k's for its j: first-max (strict >, asc k)
        float best = -__builtin_inff();
        int bidx = seg * KSEG;
        #pragma unroll
        for (int u = 0; u < 16; ++u) {
            float4 q  = *(const float4*)(rowp + u * 4);   // 16-lane broadcast
            float4 wv = latr[u];
            int k0 = seg * KSEG + u * 4;
            float v0 = q.x + wv.x;
            float v1 = q.y + wv.y;
            float v2 = q.z + wv.z;
            float v3 = q.w + wv.w;
            if (v0 > best) { best = v0; bidx = k0;     }
            if (v1 > best) { best = v1; bidx = k0 + 1; }
            if (v2 > best) { best = v2; bidx = k0 + 2; }
            if (v3 > best) { best = v3; bidx = k0 + 3; }
        }

        // ---- combine the wave's 4 segs per j via shfl (disjoint ascending k
        // ranges: tie -> smaller bidx == sequential first-max). No sync.
        {
            float ov = __shfl_xor(best, 16);
            int   oi = __shfl_xor(bidx, 16);
            if (ov > best || (ov == best && oi < bidx)) { best = ov; bidx = oi; }
            ov = __shfl_xor(best, 32);
            oi = __shfl_xor(bidx, 32);
            if (ov > best || (ov == best && oi < bidx)) { best = ov; bidx = oi; }
        }
        if ((tid & 63) < JPB) {                 // one lane per (wave, jj)
            smaxw[wav][jj] = best;
            sidxw[wav][jj] = (unsigned short)bidx;
        }
        __syncthreads();                        // barrier 2: partials visible

        // ---- final 4-deep combine (ascending wave == ascending seg) + publish
        if (tid < JPB) {
            float m = smaxw[0][tid];
            int  mi = sidxw[0][tid];
            #pragma unroll
            for (int ww = 1; ww < 4; ++ww) {
                float v = smaxw[ww][tid];
                if (v > m) { m = v; mi = sidxw[ww][tid]; }
            }
            int jw = j0 + tid;
            // reference quirk: j==0 forced from state 0; prevs[0] (staged by
            // tid 0, wave 0 -- not yet overwritten) is cols[t-1][0].
            float val = (jw == 0) ? (prevs[0] + lat00) : m;
            // emission sum, ascending d (bit-identical to reference order)
            float acc = 0.0f;
            #pragma unroll
            for (int d = 0; d < DD; ++d) acc += elp[t & 1][tid][d];
            float out = val + acc;
            __hip_atomic_store((u32*)(cols + (size_t)t * NSTATES) + jw,
                               __float_as_uint(out), __ATOMIC_RELAXED,
                               __HIP_MEMORY_SCOPE_AGENT);
            bptr[(size_t)t * NSTATES + jw] = (unsigned short)mi;
        }
        // no third barrier: next iteration's staging/elp writes only overwrite
        // buffers whose readers completed before barrier 2 (elp is 2-deep);
        // smaxw reuse is ordered by the next iteration's barrier 1.
    }
}

// Double-buffered backtrace (verified in rounds 6-7): 255 threads stage
// chunk c+1 from HBM while lane 0 chases chunk c through LDS.
#define BTC 16  // ptr rows per LDS chunk; 2 buffers x 16 rows x 2KB = 64 KB
__global__ void k_backtrace(const float* __restrict__ lastcol,
                            const unsigned short* __restrict__ bptr,
                            int* __restrict__ seq)
{
    __shared__ unsigned short ring[2][BTC][NSTATES];
    __shared__ int s_front;
    const int tid = threadIdx.x;    // 256 threads

    // last = first-max argmax over final column (wave 0)
    if (tid < 64) {
        float best = -__builtin_inff();
        int bi = 0;
        for (int n2 = tid; n2 < NSTATES; n2 += 64) {
            float v = lastcol[n2];
            if (v > best) { best = v; bi = n2; }
        }
        #pragma unroll
        for (int off = 32; off > 0; off >>= 1) {
            float ov = __shfl_xor(best, off);
            int   oi = __shfl_xor(bi, off);
            if (ov > best || (ov == best && oi < bi)) { best = ov; bi = oi; }
        }
        if (tid == 0) { seq[TT] = bi; seq[TT - 1] = bi; s_front = bi; }
    }
    __syncthreads();

    // chunks descend: chunk c covers rows rhi=TT-1-c*BTC .. max(rhi-BTC+1, 1).
    auto stage = [&](int c, int buf, int t0, int stride) {
        int rhi = TT - 1 - c * BTC;
        int rlo = rhi - (BTC - 1); if (rlo < 1) rlo = 1;
        int n4 = (rhi - rlo + 1) * 128;                 // uint4 per chunk
        uint4* dst = (uint4*)&ring[buf][0][0];
        for (int idx = t0; idx < n4; idx += stride) {
            int ro = idx >> 7, wo = idx & 127;
            dst[idx] = ((const uint4*)(bptr + (size_t)(rhi - ro) * NSTATES))[wo];
        }
    };
    const int nc = (TT - 1 + BTC - 1) / BTC;            // 256
    stage(0, 0, tid, 256);
    __syncthreads();
    for (int c = 0; c < nc; ++c) {
        int buf = c & 1;
        if (tid != 0) {
            if (c + 1 < nc) stage(c + 1, buf ^ 1, tid - 1, 255);
        } else {
            int rhi = TT - 1 - c * BTC;
            int rlo = rhi - (BTC - 1); if (rlo < 1) rlo = 1;
            int front = s_front;
            for (int r = rhi; r >= rlo; --r) {
                front = (int)ring[buf][rhi - r][front];
                seq[r - 1] = front;
            }
            s_front = front;
        }
        __syncthreads();
    }
}

extern "C" void kernel_launch(void* const* d_in, const int* in_sizes, int n_in,
                              void* d_out, int out_size, void* d_ws, size_t ws_size,
                              hipStream_t stream) {
    const float* ev    = (const float*)d_in[0];   // [T, D]
    const float* prior = (const float*)d_in[1];   // [N]
    const float* tr    = (const float*)d_in[2];   // [N, N]
    const float* epar  = (const float*)d_in[3];   // [N, D, 2]
    int* seq = (int*)d_out;                       // [T+1]
    char* ws = (char*)d_ws;
    float* lat  = (float*)(ws + OFF_LAT);
    float* cols = (float*)(ws + OFF_COLS);
    unsigned short* bptr = (unsigned short*)(ws + OFF_PTR);

    k_init<<<4096, 256, 0, stream>>>((uint4*)cols);              // sentinel-fill 16 MB
    k_logtrans<<<4096, 256, 0, stream>>>(tr, lat);
    k_forward<<<FW_BLOCKS, FW_THREADS, 0, stream>>>(lat, ev, epar, prior, cols, bptr);
    k_backtrace<<<1, 256, 0, stream>>>(cols + (size_t)(TT - 1) * NSTATES, bptr, seq);
}